// Round 1
// baseline (401.546 us; speedup 1.0000x reference)
//
#include <hip/hip_runtime.h>

#define BATCH 8
#define SEQ   2048
#define DIM   1024   // D == H == 1024

typedef __attribute__((ext_vector_type(8)))  short short8;
typedef __attribute__((ext_vector_type(4)))  short short4v;
typedef __attribute__((ext_vector_type(4)))  float floatx4;
typedef __attribute__((ext_vector_type(16))) float floatx16;

__device__ __forceinline__ unsigned short f32_to_bf16(float f) {
    union { float f; unsigned int u; } x; x.f = f;
    unsigned int r = x.u + 0x7fffu + ((x.u >> 16) & 1u);
    return (unsigned short)(r >> 16);
}

__device__ __forceinline__ float bf16_to_f32(unsigned short h) {
    union { unsigned int u; float f; } x; x.u = ((unsigned int)h) << 16;
    return x.f;
}

// async 16B/lane global->LDS. LDS base wave-uniform; HW scatters lane i at base+16*i.
__device__ __forceinline__ void async_load16(const void* g, void* l) {
    __builtin_amdgcn_global_load_lds(
        (const __attribute__((address_space(1))) void*)g,
        (__attribute__((address_space(3))) void*)l, 16, 0, 0);
}

// ---------------------------------------------------------------------------
// per-batch compaction: idx[b][0..cnt) = rows with mask>0.5 (ascending),
// pads idx[cnt..SEQ) = 0; cnt[b]; padcnt[b] = round-up-128(cnt).
// ---------------------------------------------------------------------------
__global__ __launch_bounds__(256) void build_idx(
    const float* __restrict__ mask, int* __restrict__ idx,
    int* __restrict__ cnt, int* __restrict__ padcnt)
{
    const int b = blockIdx.x;
    const int t = threadIdx.x;
    const float* mb = mask + b * SEQ;
    int flags[8]; int c = 0;
#pragma unroll
    for (int j = 0; j < 8; ++j) {
        flags[j] = (mb[t * 8 + j] > 0.5f) ? 1 : 0;
        c += flags[j];
    }
    int sc = c;                       // inclusive scan within wave
    for (int o = 1; o < 64; o <<= 1) {
        int v = __shfl_up(sc, o);
        if ((t & 63) >= o) sc += v;
    }
    __shared__ int wtot[4];
    const int lane = t & 63, wave = t >> 6;
    if (lane == 63) wtot[wave] = sc;
    __syncthreads();
    int woff = 0;
    for (int w = 0; w < wave; ++w) woff += wtot[w];
    int p = woff + sc - c;            // exclusive offset
#pragma unroll
    for (int j = 0; j < 8; ++j)
        if (flags[j]) idx[b * SEQ + (p++)] = t * 8 + j;
    __syncthreads();
    const int total = wtot[0] + wtot[1] + wtot[2] + wtot[3];
    if (t == 0) { cnt[b] = total; padcnt[b] = (total + 127) & ~127; }
    for (int q = total + t; q < SEQ; q += 256) idx[b * SEQ + q] = 0;
}

// ---------------------------------------------------------------------------
// gather unmasked input_q rows (f32) -> compacted bf16 rows
// ---------------------------------------------------------------------------
__global__ __launch_bounds__(256) void gather_cvt_q(
    const float* __restrict__ xq, const int* __restrict__ idx,
    const int* __restrict__ padcnt, unsigned short* __restrict__ qc)
{
    const int b = blockIdx.y;
    const int rc = blockIdx.x;
    if (rc >= padcnt[b]) return;
    const int src = idx[b * SEQ + rc];
    const float* s = xq + ((long)b * SEQ + src) * DIM + threadIdx.x * 4;
    unsigned short* d = qc + ((long)b * SEQ + rc) * DIM + threadIdx.x * 4;
    floatx4 v = *(const floatx4*)s;
    short4v w;
#pragma unroll
    for (int j = 0; j < 4; ++j) w[j] = (short)f32_to_bf16(v[j]);
    *(short4v*)d = w;
}

// ---------------------------------------------------------------------------
// fused single pass over input_k:
//   kbf = bf16(input_k)  (straight layout)
//   Vt  = bf16(input_k)^T per batch (DIM x SEQ)
//   mavg += masked column partial sums
// grid (DIM/32, SEQ/32, BATCH), block 256 (32x8)
// ---------------------------------------------------------------------------
__global__ __launch_bounds__(256) void prep_kv(
    const float* __restrict__ xk, const float* __restrict__ mask,
    unsigned short* __restrict__ kbf, unsigned short* __restrict__ Vt,
    float* __restrict__ mavg)
{
    __shared__ float tile[32][33];
    __shared__ float msk[32];
    __shared__ float csum[8][32];
    const int b  = blockIdx.z;
    const int c0 = blockIdx.x * 32;   // dim cols
    const int r0 = blockIdx.y * 32;   // seq rows
    const int tx = threadIdx.x & 31, ty = threadIdx.x >> 5;   // ty 0..7
    const float* xb = xk + (long)b * SEQ * DIM;
    unsigned short* kb = kbf + (long)b * SEQ * DIM;
    unsigned short* vb = Vt + (long)b * DIM * SEQ;

    if (threadIdx.x < 32) msk[threadIdx.x] = mask[b * SEQ + r0 + threadIdx.x];

    float v[4];
#pragma unroll
    for (int i = 0; i < 4; ++i) {
        const int r = ty + i * 8;
        v[i] = xb[(long)(r0 + r) * DIM + c0 + tx];
        tile[r][tx] = v[i];
        kb[(long)(r0 + r) * DIM + c0 + tx] = f32_to_bf16(v[i]);
    }
    __syncthreads();

    float s = 0.f;
#pragma unroll
    for (int i = 0; i < 4; ++i) {
        const int r = ty + i * 8;
        s += (msk[r] <= 0.5f) ? v[i] : 0.f;
    }
    csum[ty][tx] = s;

#pragma unroll
    for (int i = 0; i < 4; ++i) {
        const int c = ty + i * 8;
        vb[(long)(c0 + c) * SEQ + r0 + tx] = f32_to_bf16(tile[tx][c]);
    }
    __syncthreads();
    if (ty == 0) {
        float t = 0.f;
#pragma unroll
        for (int j = 0; j < 8; ++j) t += csum[j][tx];
        atomicAdd(&mavg[b * DIM + c0 + tx], t);
    }
}

// ---------------------------------------------------------------------------
// f32 -> bf16 bulk convert, 8 elems/thread
// ---------------------------------------------------------------------------
__global__ __launch_bounds__(256) void cvt_bf16(
    const float* __restrict__ src, unsigned short* __restrict__ dst)
{
    const long i = ((long)blockIdx.x * 256 + threadIdx.x) * 8;
    floatx4 v0 = *(const floatx4*)(src + i);
    floatx4 v1 = *(const floatx4*)(src + i + 4);
    short8 w;
#pragma unroll
    for (int j = 0; j < 4; ++j) w[j]     = (short)f32_to_bf16(v0[j]);
#pragma unroll
    for (int j = 0; j < 4; ++j) w[4 + j] = (short)f32_to_bf16(v1[j]);
    *(short8*)(dst + i) = w;
}

// ---------------------------------------------------------------------------
// g0[d] = sum_h bq[h] * Wk[d,h]   (Wk row-major (D,H)); one block per d
// ---------------------------------------------------------------------------
__global__ __launch_bounds__(256) void proj_bias(
    const float* __restrict__ bq, const float* __restrict__ Wk, float* __restrict__ g0)
{
    const int n = blockIdx.x;
    const int t = threadIdx.x;
    float s = 0.f;
    for (int h = t; h < DIM; h += 256) s += bq[h] * Wk[(long)n * DIM + h];
    for (int o = 32; o; o >>= 1) s += __shfl_xor(s, o);
    __shared__ float r[4];
    if ((t & 63) == 0) r[t >> 6] = s;
    __syncthreads();
    if (t == 0) g0[n] = r[0] + r[1] + r[2] + r[3];
}

// ---------------------------------------------------------------------------
// C = A @ B^T (+bias) * scale.  A: MxK bf16, Bt: NxK bf16, C: MxN (bf16|f32).
// 128x128 block tile, BK=64, 256 threads (4 waves 2x2), each wave 64x64 via
// 2x2 v_mfma_f32_32x32x16_bf16.  XOR-swizzled LDS staging.
//
// R1: DOUBLE-BUFFERED LDS (2x32KB) + raw s_barrier + counted vmcnt pipeline.
//   segment t: read slot[t&1] frags -> lgkmcnt(0) -> B1 -> stage tile t+2
//   into slot[t&1] (region just fully consumed) -> MFMA -> vmcnt(8) (tile
//   t+1 landed, t+2's 8 loads stay in flight) -> B2.  Latency cover for a
//   tile = ~1.5 segments instead of the old 0 (sync drained every step).
//   sched_barrier(0) after each inline waitcnt per rule #18.
//
// FLAT grid modes (XCD locality): 0 = normal 3D grid.
//   1 = flat 1D, batch = id&7 (pins batch->XCD), x = rem & ((1<<sh)-1), y = rem>>sh
//   2 = flat 1D, batch = id&7, y = rem & ((1<<sh)-1), x = rem>>sh
// LIMIT: skip row-blocks past mlim[z].  SCATTER: row -> idx[z][row], < cnt[z].
// ---------------------------------------------------------------------------
template<bool C_BF16, bool BIAS, bool LIMIT, bool SCATTER, int FLAT>
__global__ __launch_bounds__(256) void gemm_bt(
    const unsigned short* __restrict__ A, const unsigned short* __restrict__ Bt,
    void* __restrict__ Cp, const float* __restrict__ bias,
    int N, int K, long sA, long sB, long sC, float scale,
    const int* __restrict__ mlim, const int* __restrict__ cntp,
    const int* __restrict__ idx, int sh)
{
    int bx, by, bz;
    if (FLAT == 0) {
        bx = blockIdx.x; by = blockIdx.y; bz = blockIdx.z;
    } else {
        const int id = blockIdx.x;
        bz = id & 7;                       // batch -> XCD (round-robin heuristic)
        const int rem = id >> 3;
        const int m = (1 << sh) - 1;
        if (FLAT == 1) { bx = rem & m; by = rem >> sh; }
        else           { by = rem & m; bx = rem >> sh; }
    }
    const int row0 = bx * 128;
    if (LIMIT && row0 >= mlim[bz]) return;

    __shared__ unsigned short As[2][128 * 64];
    __shared__ unsigned short Bs[2][128 * 64];

    const int tid  = threadIdx.x;
    const int lane = tid & 63;
    const int wave = tid >> 6;
    const int wm   = wave >> 1;       // 0..1
    const int wn   = wave & 1;        // 0..1
    const int l31  = lane & 31;
    const int half = lane >> 5;       // 0..1
    const int x7   = lane & 7;
    const int col0 = by * 128;
    const long zA = (long)bz * sA;
    const long zB = (long)bz * sB;
    const long zC = (long)bz * sC;

    // staging: one async chunk = 1KB = 8 rows x 128B. lane i -> row sr=i>>3,
    // LDS slot i&7; global k-chunk sq = (i&7)^sr (XOR swizzle, in shorts*8)
    const int sr = lane >> 3;                  // 0..7
    const int sq = ((lane & 7) ^ sr) * 8;      // shorts

    const unsigned short* Abase = A  + zA + (long)row0 * K;
    const unsigned short* Bbase = Bt + zB + (long)col0 * K;
    const unsigned short* aptr[4];
    const unsigned short* bptr[4];
#pragma unroll
    for (int c = 0; c < 4; ++c) {
        const int r = (wave * 4 + c) * 8 + sr;   // 0..127
        aptr[c] = Abase + (long)r * K + sq;
        bptr[c] = Bbase + (long)r * K + sq;
    }

    // issue one tile's staging (8 global_load_lds per wave) into slot
    auto stage = [&](int slot, int ktElem) {
#pragma unroll
        for (int c = 0; c < 4; ++c) {
            const int chunk = wave * 4 + c;
            async_load16(aptr[c] + ktElem, &As[slot][chunk * 512]);
            async_load16(bptr[c] + ktElem, &Bs[slot][chunk * 512]);
        }
    };

    floatx16 acc[2][2];
#pragma unroll
    for (int a = 0; a < 2; ++a)
#pragma unroll
        for (int b = 0; b < 2; ++b)
#pragma unroll
            for (int r = 0; r < 16; ++r) acc[a][b][r] = 0.f;

    // fragment row bases (shorts): row stride 64
    const int raf[2] = { (wm * 64 +  0 + l31) * 64, (wm * 64 + 32 + l31) * 64 };
    const int rbf[2] = { (wn * 64 +  0 + l31) * 64, (wn * 64 + 32 + l31) * 64 };

    const int NT = K >> 6;

    // prologue: fill both slots, wait tile0 only (tile1's 8 stay in flight)
    stage(0, 0);
    if (NT > 1) {
        stage(1, 64);
        asm volatile("s_waitcnt vmcnt(8)" ::: "memory");
    } else {
        asm volatile("s_waitcnt vmcnt(0)" ::: "memory");
    }
    __builtin_amdgcn_sched_barrier(0);
    __builtin_amdgcn_s_barrier();
    __builtin_amdgcn_sched_barrier(0);

    for (int t = 0; t < NT; ++t) {
        const int cur = t & 1;
        const unsigned short* Ac = &As[cur][0];
        const unsigned short* Bc = &Bs[cur][0];

        // ---- group 0: ks 0,1 ----
        short8 af[2][2], bf[2][2];
#pragma unroll
        for (int ks = 0; ks < 2; ++ks) {
            const int sw = ((ks * 2 + half) ^ x7) << 3;   // swizzled 16B slot
#pragma unroll
            for (int tt = 0; tt < 2; ++tt) {
                af[ks][tt] = *(const short8*)(Ac + raf[tt] + sw);
                bf[ks][tt] = *(const short8*)(Bc + rbf[tt] + sw);
            }
        }
        asm volatile("s_waitcnt lgkmcnt(0)" ::: "memory");
        __builtin_amdgcn_sched_barrier(0);
        __builtin_amdgcn_s_setprio(1);
#pragma unroll
        for (int ks = 0; ks < 2; ++ks)
#pragma unroll
            for (int tm = 0; tm < 2; ++tm)
#pragma unroll
                for (int tn = 0; tn < 2; ++tn)
                    acc[tm][tn] = __builtin_amdgcn_mfma_f32_32x32x16_bf16(
                        af[ks][tm], bf[ks][tn], acc[tm][tn], 0, 0, 0);
        __builtin_amdgcn_s_setprio(0);

        // ---- group 1: ks 2,3 (reuses frag registers) ----
#pragma unroll
        for (int ks = 0; ks < 2; ++ks) {
            const int sw = (((ks + 2) * 2 + half) ^ x7) << 3;
#pragma unroll
            for (int tt = 0; tt < 2; ++tt) {
                af[ks][tt] = *(const short8*)(Ac + raf[tt] + sw);
                bf[ks][tt] = *(const short8*)(Bc + rbf[tt] + sw);
            }
        }
        asm volatile("s_waitcnt lgkmcnt(0)" ::: "memory");
        __builtin_amdgcn_sched_barrier(0);
        // B1: all waves have retired their reads of slot[cur] -> safe to
        // overwrite it with tile t+2's staging.
        __builtin_amdgcn_s_barrier();
        __builtin_amdgcn_sched_barrier(0);
        if (t + 2 < NT) stage(cur, (t + 2) * 64);
        __builtin_amdgcn_sched_barrier(0);
        __builtin_amdgcn_s_setprio(1);
#pragma unroll
        for (int ks = 0; ks < 2; ++ks)
#pragma unroll
            for (int tm = 0; tm < 2; ++tm)
#pragma unroll
                for (int tn = 0; tn < 2; ++tn)
                    acc[tm][tn] = __builtin_amdgcn_mfma_f32_32x32x16_bf16(
                        af[ks][tm], bf[ks][tn], acc[tm][tn], 0, 0, 0);
        __builtin_amdgcn_s_setprio(0);

        if (t + 1 < NT) {
            // wait tile t+1's 8 loads; tile t+2's 8 (if staged) stay in flight
            if (t + 2 < NT) asm volatile("s_waitcnt vmcnt(8)" ::: "memory");
            else            asm volatile("s_waitcnt vmcnt(0)" ::: "memory");
            __builtin_amdgcn_sched_barrier(0);
            __builtin_amdgcn_s_barrier();    // B2: tile t+1 visible to all
            __builtin_amdgcn_sched_barrier(0);
        }
    }

    // epilogue: 32x32 C/D layout col=lane&31, row=(reg&3)+8*(reg>>2)+4*(lane>>5)
    const int climit = SCATTER ? cntp[bz] : 0;
    const int* ridx  = SCATTER ? (idx + bz * SEQ) : (const int*)nullptr;
#pragma unroll
    for (int tn = 0; tn < 2; ++tn) {
        const int ccol = col0 + wn * 64 + tn * 32 + l31;
        float bv = 0.f;
        if (BIAS) bv = bias[ccol];
#pragma unroll
        for (int tm = 0; tm < 2; ++tm) {
            const int rbase = row0 + wm * 64 + tm * 32 + 4 * half;
#pragma unroll
            for (int r = 0; r < 16; ++r) {
                const int crow = rbase + (r & 3) + 8 * (r >> 2);
                float v = acc[tm][tn][r] * scale + bv;
                long orow = crow;
                if (SCATTER) {
                    if (crow >= climit) continue;
                    orow = ridx[crow];
                }
                const long ci = zC + orow * (long)N + ccol;
                if (C_BF16) ((unsigned short*)Cp)[ci] = f32_to_bf16(v);
                else        ((float*)Cp)[ci] = v;
            }
        }
    }
}

// ---------------------------------------------------------------------------
// in-place row softmax over 2048 bf16 scores; one block per compacted row
// ---------------------------------------------------------------------------
__global__ __launch_bounds__(256) void softmax_rows(
    unsigned short* __restrict__ S, const int* __restrict__ padcnt)
{
    const int b = blockIdx.x >> 11, rc = blockIdx.x & 2047;
    if (rc >= padcnt[b]) return;
    const long base = (long)blockIdx.x * SEQ + threadIdx.x * 8;
    const int lane = threadIdx.x & 63, wave = threadIdx.x >> 6;
    __shared__ float rbuf[8];

    short8 v = *(const short8*)(S + base);
    float x[8];
#pragma unroll
    for (int j = 0; j < 8; ++j) x[j] = bf16_to_f32((unsigned short)v[j]);

    float m = x[0];
#pragma unroll
    for (int j = 1; j < 8; ++j) m = fmaxf(m, x[j]);
    for (int o = 32; o; o >>= 1) m = fmaxf(m, __shfl_xor(m, o));
    if (lane == 0) rbuf[wave] = m;
    __syncthreads();
    m = fmaxf(fmaxf(rbuf[0], rbuf[1]), fmaxf(rbuf[2], rbuf[3]));

    float e[8], s = 0.f;
#pragma unroll
    for (int j = 0; j < 8; ++j) { e[j] = __expf(x[j] - m); s += e[j]; }
    for (int o = 32; o; o >>= 1) s += __shfl_xor(s, o);
    if (lane == 0) rbuf[4 + wave] = s;
    __syncthreads();
    s = rbuf[4] + rbuf[5] + rbuf[6] + rbuf[7];
    const float inv = 1.0f / s;

    short8 o8;
#pragma unroll
    for (int j = 0; j < 8; ++j) o8[j] = (short)f32_to_bf16(e[j] * inv);
    *(short8*)(S + base) = o8;
}

// ---------------------------------------------------------------------------
// rows with mask<=0.5: out[b,i,:] = mavg[b,:]/masked_count  (exact fp32 path)
// ---------------------------------------------------------------------------
__global__ __launch_bounds__(256) void overwrite_masked(
    float* __restrict__ out, const float* __restrict__ mask,
    const float* __restrict__ mavg, const int* __restrict__ cnt)
{
    const int bid = blockIdx.x;            // b*SEQ + i
    const int b = bid >> 11;
    if (mask[bid] > 0.5f) return;
    const float inv = 1.0f / (float)(SEQ - cnt[b]);
    const long obase = (long)bid * DIM;
    const float* mv = mavg + b * DIM;
    for (int d = threadIdx.x; d < DIM; d += 256)
        out[obase + d] = mv[d] * inv;
}

extern "C" void kernel_launch(void* const* d_in, const int* in_sizes, int n_in,
                              void* d_out, int out_size, void* d_ws, size_t ws_size,
                              hipStream_t stream) {
    (void)in_sizes; (void)n_in; (void)out_size;
    const float* input_q = (const float*)d_in[0];
    const float* input_k = (const float*)d_in[1];
    const float* k_mask  = (const float*)d_in[2];
    const float* Wq      = (const float*)d_in[3];
    const float* bq      = (const float*)d_in[4];
    const float* Wk      = (const float*)d_in[5];
    const float* bk      = (const float*)d_in[6];
    (void)bk;   // bk shifts each score row by a constant -> softmax-invariant
    float* out = (float*)d_out;

    // Workspace map (aliases sequenced by stream order):
    //   qc   aliases S lo 32MB      (dead once qpp computed, before scores writes S)
    //   Wqb/Wkb alias qpp lo 4MB    (dead once Gt computed, before qpp written)
    char* ws = (char*)d_ws;
    unsigned short* qc   = (unsigned short*)(ws);                 // 32MB
    unsigned short* S    = (unsigned short*)(ws);                 // 64MB
    unsigned short* qpp  = (unsigned short*)(ws + 67108864);      // 32MB
    unsigned short* Wqb  = (unsigned short*)(ws + 67108864);      // 2MB (alias)
    unsigned short* Wkb  = (unsigned short*)(ws + 69206016);      // 2MB (alias)
    unsigned short* kbf  = (unsigned short*)(ws + 100663296);     // 32MB
    unsigned short* Vt   = (unsigned short*)(ws + 134217728);     // 32MB
    unsigned short* Gt   = (unsigned short*)(ws + 167772160);     // 2MB
    float*          g0   = (float*)(ws + 169869312);              // 4KB
    float*          mavg = (float*)(ws + 169873408);              // 32KB
    int*            idx  = (int*)(ws + 169906176);                // 64KB
    int*            cnts = (int*)(ws + 169971712);                // 32B
    int*            pcnt = (int*)(ws + 169971744);                // 32B
    if (ws_size < 169971776) return;

    hipMemsetAsync(mavg, 0, BATCH * DIM * sizeof(float), stream);

    build_idx<<<BATCH, 256, 0, stream>>>(k_mask, idx, cnts, pcnt);
    gather_cvt_q<<<dim3(SEQ, BATCH), 256, 0, stream>>>(input_q, idx, pcnt, qc);
    prep_kv<<<dim3(DIM / 32, SEQ / 32, BATCH), 256, 0, stream>>>(input_k, k_mask, kbf, Vt, mavg);
    cvt_bf16<<<512, 256, 0, stream>>>(Wq, Wqb);
    cvt_bf16<<<512, 256, 0, stream>>>(Wk, Wkb);
    proj_bias<<<DIM, 256, 0, stream>>>(bq, Wk, g0);

    // Gt[d,e] = sum_h Wk[d,h] * Wq[e,h]   (combined projection, 1024^3)
    gemm_bt<true, false, false, false, 0><<<dim3(8, 8, 1), 256, 0, stream>>>(
        Wkb, Wqb, Gt, nullptr, DIM, DIM, 0, 0, 0, 1.0f, nullptr, nullptr, nullptr, 0);

    // q''[m,d] = sum_e qc[m,e] * Gt[d,e] + g0[d]   (compacted; batch->XCD, y-fast ny=8)
    gemm_bt<true, true, true, false, 2><<<8 * 16 * 8, 256, 0, stream>>>(
        qc, Gt, qpp, g0, DIM, DIM,
        (long)SEQ * DIM, 0, (long)SEQ * DIM, 1.0f, pcnt, nullptr, nullptr, 3);

    // scores: S[i,j] = q''[i,:] . kbf[j,:] / 32 -> bf16  (batch->XCD, x-fast nx=16)
    gemm_bt<true, false, true, false, 1><<<8 * 16 * 16, 256, 0, stream>>>(
        qpp, kbf, S, nullptr, SEQ, DIM,
        (long)SEQ * DIM, (long)SEQ * DIM, (long)SEQ * SEQ, 0.03125f, pcnt, nullptr, nullptr, 4);

    softmax_rows<<<BATCH * SEQ, 256, 0, stream>>>(S, pcnt);

    // out rows (scattered): per batch P @ V  (batch->XCD, y-fast ny=8)
    gemm_bt<false, false, true, true, 2><<<8 * 16 * 8, 256, 0, stream>>>(
        S, Vt, out, nullptr, DIM, SEQ,
        (long)SEQ * SEQ, (long)DIM * SEQ, (long)SEQ * DIM, 1.0f, pcnt, cnts, idx, 3);

    overwrite_masked<<<BATCH * SEQ, 256, 0, stream>>>(out, k_mask, mavg, cnts);
}